// Round 1
// baseline (358.950 us; speedup 1.0000x reference)
//
#include <hip/hip_runtime.h>

#define B 8
#define N 2048
#define M 2048
#define DIN 256
#define E 128
#define ALPHA 0.01f

// ---------------------------------------------------------------------------
// K0: v1[k] = sum_e W1[k][e]*a1[e], v2[k] = sum_e W1[k][e]*a1[128+e]
// Folds att1 = (in1@W1)@a1_lo into in1@(W1@a1_lo) — Wh1 never materialized.
// ---------------------------------------------------------------------------
__global__ __launch_bounds__(256) void prep_v_kernel(
    const float* __restrict__ W1, const float* __restrict__ a1,
    float* __restrict__ v1, float* __restrict__ v2) {
  int k = threadIdx.x;  // 0..255
  float s1 = 0.f, s2 = 0.f;
#pragma unroll 8
  for (int e = 0; e < E; ++e) {
    float w = W1[k * E + e];
    s1 += w * a1[e];
    s2 += w * a1[E + e];
  }
  v1[k] = s1;
  v2[k] = s2;
}

// ---------------------------------------------------------------------------
// K1: att1[row] = dot(input1[row,:], v1); att2 likewise. One wave per row.
// rows 0..16383 -> input1/att1, rows 16384..32767 -> input2/att2.
// ---------------------------------------------------------------------------
__global__ __launch_bounds__(256) void att_kernel(
    const float* __restrict__ in1, const float* __restrict__ in2,
    const float* __restrict__ v1, const float* __restrict__ v2,
    float* __restrict__ att1, float* __restrict__ att2) {
  int wave = blockIdx.x * 4 + (threadIdx.x >> 6);
  int lane = threadIdx.x & 63;
  const float* src;
  const float* v;
  float* dst;
  int row;
  if (wave < B * N) {
    src = in1; v = v1; dst = att1; row = wave;
  } else {
    src = in2; v = v2; dst = att2; row = wave - B * N;
  }
  float4 x = *(const float4*)(src + (size_t)row * DIN + lane * 4);
  float4 vv = *(const float4*)(v + lane * 4);
  float d = x.x * vv.x + x.y * vv.y + x.z * vv.z + x.w * vv.w;
#pragma unroll
  for (int off = 32; off; off >>= 1) d += __shfl_down(d, off, 64);
  if (lane == 0) dst[row] = d;
}

// ---------------------------------------------------------------------------
// K2: Wh2 = input2 @ W1   (16384x256 @ 256x128, fp32)
// Tile: 32 rows x 128 cols per block of 256 threads; full K=256 staged in LDS.
// ---------------------------------------------------------------------------
__global__ __launch_bounds__(256) void wh2_kernel(
    const float* __restrict__ in2, const float* __restrict__ W1,
    float* __restrict__ Wh2) {
  __shared__ float a[32][DIN];  // 32 KB
  int r0 = blockIdx.x * 32;
  // stage 32x256 input tile, coalesced float4
#pragma unroll
  for (int i = 0; i < 8; ++i) {
    int f = (threadIdx.x + i * 256) * 4;
    int r = f >> 8, k = f & 255;
    *(float4*)&a[r][k] = *(const float4*)(in2 + (size_t)(r0 + r) * DIN + k);
  }
  __syncthreads();
  int c  = (threadIdx.x & 31) * 4;   // col base
  int tr = (threadIdx.x >> 5) * 4;   // row base (0..28)
  float acc[4][4] = {};
  for (int k = 0; k < DIN; ++k) {
    float4 b = *(const float4*)(W1 + k * E + c);  // L1/L2-hot, coalesced
#pragma unroll
    for (int r = 0; r < 4; ++r) {
      float av = a[tr + r][k];  // 2 addrs per wave -> LDS broadcast
      acc[r][0] += av * b.x;
      acc[r][1] += av * b.y;
      acc[r][2] += av * b.z;
      acc[r][3] += av * b.w;
    }
  }
#pragma unroll
  for (int r = 0; r < 4; ++r)
    *(float4*)(Wh2 + (size_t)(r0 + tr + r) * E + c) =
        make_float4(acc[r][0], acc[r][1], acc[r][2], acc[r][3]);
}

// ---------------------------------------------------------------------------
// K3: per-row softmax of LeakyReLU(att1[n]+att2[m]) + mask[m]; writes probs.
// One block of 256 threads per row (8 m-values per thread).
// ---------------------------------------------------------------------------
__global__ __launch_bounds__(256) void softmax_kernel(
    const float* __restrict__ att1, const float* __restrict__ att2,
    const float* __restrict__ mask, float* __restrict__ probs) {
  int row = blockIdx.x;  // b*N + n
  int b = row >> 11;
  float a1v = att1[row];
  __shared__ float red[8];
  float s[8];
  float mx = -1e30f;
#pragma unroll
  for (int j = 0; j < 8; ++j) {
    int m = j * 256 + threadIdx.x;
    float t = a1v + att2[b * M + m];
    t = t > 0.f ? t : ALPHA * t;       // LeakyReLU BEFORE mask (matches ref)
    t += mask[b * M + m];
    s[j] = t;
    mx = fmaxf(mx, t);
  }
#pragma unroll
  for (int off = 32; off; off >>= 1) mx = fmaxf(mx, __shfl_xor(mx, off, 64));
  int wid = threadIdx.x >> 6;
  if ((threadIdx.x & 63) == 0) red[wid] = mx;
  __syncthreads();
  mx = fmaxf(fmaxf(red[0], red[1]), fmaxf(red[2], red[3]));
  float sum = 0.f;
#pragma unroll
  for (int j = 0; j < 8; ++j) {
    s[j] = __expf(s[j] - mx);
    sum += s[j];
  }
#pragma unroll
  for (int off = 32; off; off >>= 1) sum += __shfl_xor(sum, off, 64);
  if ((threadIdx.x & 63) == 0) red[4 + wid] = sum;
  __syncthreads();
  sum = red[4] + red[5] + red[6] + red[7];
  float inv = 1.f / sum;
#pragma unroll
  for (int j = 0; j < 8; ++j) {
    int m = j * 256 + threadIdx.x;
    probs[(size_t)row * M + m] = s[j] * inv;  // coalesced
  }
}

// ---------------------------------------------------------------------------
// K4: context = probs @ Wh2 per batch (2048x2048 @ 2048x128, fp32 tiled).
// 32-row x 128-col tile per block, BK=32; probs re-read is L3-resident.
// ---------------------------------------------------------------------------
__global__ __launch_bounds__(256) void context_kernel(
    const float* __restrict__ probs, const float* __restrict__ Wh2,
    float* __restrict__ ctx) {
  __shared__ float pt[32][36];   // [k][row], pad 36 -> 16B-aligned float4 rows
  __shared__ float wt[32][E];    // 16 KB
  int rt = blockIdx.x & 63;
  int b = blockIdx.x >> 6;
  int row0 = b * N + rt * 32;    // global row base for probs & ctx
  int c  = (threadIdx.x & 31) * 4;
  int tr = (threadIdx.x >> 5) * 4;
  float acc[4][4] = {};
  for (int m0 = 0; m0 < M; m0 += 32) {
    {  // stage P tile transposed: 32 rows x 32 k
      int f = threadIdx.x * 4;
      int r = f >> 5;    // 0..31
      int k = f & 31;
      float4 p4 = *(const float4*)(probs + (size_t)(row0 + r) * M + m0 + k);
      pt[k + 0][r] = p4.x;
      pt[k + 1][r] = p4.y;
      pt[k + 2][r] = p4.z;
      pt[k + 3][r] = p4.w;
    }
#pragma unroll
    for (int i = 0; i < 4; ++i) {  // stage Wh2 tile 32 x 128
      int f = (threadIdx.x + i * 256) * 4;
      int r = f >> 7, cc = f & 127;
      *(float4*)&wt[r][cc] =
          *(const float4*)(Wh2 + (size_t)(b * M + m0 + r) * E + cc);
    }
    __syncthreads();
#pragma unroll 8
    for (int k = 0; k < 32; ++k) {
      float4 av = *(const float4*)&pt[k][tr];  // 2 addrs/wave -> broadcast
      float4 bv = *(const float4*)&wt[k][c];
      acc[0][0] += av.x * bv.x; acc[0][1] += av.x * bv.y;
      acc[0][2] += av.x * bv.z; acc[0][3] += av.x * bv.w;
      acc[1][0] += av.y * bv.x; acc[1][1] += av.y * bv.y;
      acc[1][2] += av.y * bv.z; acc[1][3] += av.y * bv.w;
      acc[2][0] += av.z * bv.x; acc[2][1] += av.z * bv.y;
      acc[2][2] += av.z * bv.z; acc[2][3] += av.z * bv.w;
      acc[3][0] += av.w * bv.x; acc[3][1] += av.w * bv.y;
      acc[3][2] += av.w * bv.z; acc[3][3] += av.w * bv.w;
    }
    __syncthreads();
  }
#pragma unroll
  for (int r = 0; r < 4; ++r)
    *(float4*)(ctx + (size_t)(row0 + tr + r) * E + c) =
        make_float4(acc[r][0], acc[r][1], acc[r][2], acc[r][3]);
}

extern "C" void kernel_launch(void* const* d_in, const int* in_sizes, int n_in,
                              void* d_out, int out_size, void* d_ws,
                              size_t ws_size, hipStream_t stream) {
  (void)in_sizes; (void)n_in; (void)out_size; (void)ws_size;
  const float* in1  = (const float*)d_in[0];  // (B,N,DIN)
  const float* in2  = (const float*)d_in[1];  // (B,M,DIN)
  const float* mask = (const float*)d_in[2];  // (B,1,M)
  const float* W1   = (const float*)d_in[3];  // (DIN,E)
  const float* a1   = (const float*)d_in[4];  // (2E,1)

  float* ws   = (float*)d_ws;
  float* v1   = ws;                 // 256
  float* v2   = v1 + DIN;           // 256
  float* att1 = v2 + DIN;           // B*N
  float* att2 = att1 + B * N;       // B*M
  float* Wh2  = att2 + B * M;       // B*M*E  (8.4 MB) -> total ws ~8.5 MB

  float* ctx   = (float*)d_out;                 // B*N*E
  float* probs = ctx + (size_t)B * N * E;       // B*N*M

  hipLaunchKernelGGL(prep_v_kernel, dim3(1), dim3(256), 0, stream, W1, a1, v1, v2);
  hipLaunchKernelGGL(att_kernel, dim3((B * N + B * M) / 4), dim3(256), 0, stream,
                     in1, in2, v1, v2, att1, att2);
  hipLaunchKernelGGL(wh2_kernel, dim3(B * M / 32), dim3(256), 0, stream,
                     in2, W1, Wh2);
  hipLaunchKernelGGL(softmax_kernel, dim3(B * N), dim3(256), 0, stream,
                     att1, att2, mask, probs);
  hipLaunchKernelGGL(context_kernel, dim3(B * N / 32), dim3(256), 0, stream,
                     probs, Wh2, ctx);
}

// Round 2
// 248.491 us; speedup vs baseline: 1.4445x; 1.4445x over previous
//
#include <hip/hip_runtime.h>

#define B 8
#define N 2048
#define M 2048
#define DIN 256
#define E 128
#define ALPHA 0.01f

typedef __attribute__((ext_vector_type(8))) short bf16x8;
typedef __attribute__((ext_vector_type(4))) float f32x4;

__device__ inline ushort f2bf(float x) {
  unsigned u = __float_as_uint(x);
  u = (u + 0x7FFFu + ((u >> 16) & 1u)) >> 16;  // RNE
  return (ushort)u;
}

// ---------------------------------------------------------------------------
// K0: v1[k] = sum_e W1[k][e]*a1[e], v2[k] = sum_e W1[k][e]*a1[128+e]
// ---------------------------------------------------------------------------
__global__ __launch_bounds__(256) void prep_v_kernel(
    const float* __restrict__ W1, const float* __restrict__ a1,
    float* __restrict__ v1, float* __restrict__ v2) {
  int k = threadIdx.x;
  float s1 = 0.f, s2 = 0.f;
#pragma unroll 8
  for (int e = 0; e < E; ++e) {
    float w = W1[k * E + e];
    s1 += w * a1[e];
    s2 += w * a1[E + e];
  }
  v1[k] = s1;
  v2[k] = s2;
}

// ---------------------------------------------------------------------------
// K1: att1[row] = dot(input1[row,:], v1); att2 likewise. One wave per row.
// ---------------------------------------------------------------------------
__global__ __launch_bounds__(256) void att_kernel(
    const float* __restrict__ in1, const float* __restrict__ in2,
    const float* __restrict__ v1, const float* __restrict__ v2,
    float* __restrict__ att1, float* __restrict__ att2) {
  int wave = blockIdx.x * 4 + (threadIdx.x >> 6);
  int lane = threadIdx.x & 63;
  const float* src;
  const float* v;
  float* dst;
  int row;
  if (wave < B * N) {
    src = in1; v = v1; dst = att1; row = wave;
  } else {
    src = in2; v = v2; dst = att2; row = wave - B * N;
  }
  float4 x = *(const float4*)(src + (size_t)row * DIN + lane * 4);
  float4 vv = *(const float4*)(v + lane * 4);
  float d = x.x * vv.x + x.y * vv.y + x.z * vv.z + x.w * vv.w;
#pragma unroll
  for (int off = 32; off; off >>= 1) d += __shfl_down(d, off, 64);
  if (lane == 0) dst[row] = d;
}

// ---------------------------------------------------------------------------
// K2: Wh2 = input2 @ W1, fp32 compute (proven), epilogue packs bf16 into
// MFMA-B-fragment layout: Wb[(m>>3)*128 + e]*8 + (m&7). One wave covers a
// full 8-row group x 128 e -> contiguous 2KB region, L2 write-combines.
// ---------------------------------------------------------------------------
__global__ __launch_bounds__(256) void wh2_kernel(
    const float* __restrict__ in2, const float* __restrict__ W1,
    ushort* __restrict__ Wb) {
  __shared__ float a[32][DIN];  // 32 KB
  int r0 = blockIdx.x * 32;
#pragma unroll
  for (int i = 0; i < 8; ++i) {
    int f = (threadIdx.x + i * 256) * 4;
    int r = f >> 8, k = f & 255;
    *(float4*)&a[r][k] = *(const float4*)(in2 + (size_t)(r0 + r) * DIN + k);
  }
  __syncthreads();
  int c  = (threadIdx.x & 31) * 4;
  int tr = (threadIdx.x >> 5) * 4;
  float acc[4][4] = {};
  for (int k = 0; k < DIN; ++k) {
    float4 b = *(const float4*)(W1 + k * E + c);
#pragma unroll
    for (int r = 0; r < 4; ++r) {
      float av = a[tr + r][k];
      acc[r][0] += av * b.x;
      acc[r][1] += av * b.y;
      acc[r][2] += av * b.z;
      acc[r][3] += av * b.w;
    }
  }
#pragma unroll
  for (int r = 0; r < 4; ++r) {
    int m = r0 + tr + r;
    size_t gbase = (size_t)(m >> 3) * 128 * 8 + (m & 7);
#pragma unroll
    for (int j = 0; j < 4; ++j)
      Wb[gbase + (size_t)(c + j) * 8] = f2bf(acc[r][j]);
  }
}

// ---------------------------------------------------------------------------
// K3: per-row softmax of LeakyReLU(att1[n]+att2[m]) + mask[m]; writes probs.
// ---------------------------------------------------------------------------
__global__ __launch_bounds__(256) void softmax_kernel(
    const float* __restrict__ att1, const float* __restrict__ att2,
    const float* __restrict__ mask, float* __restrict__ probs) {
  int row = blockIdx.x;
  int b = row >> 11;
  float a1v = att1[row];
  __shared__ float red[8];
  float s[8];
  float mx = -1e30f;
#pragma unroll
  for (int j = 0; j < 8; ++j) {
    int m = j * 256 + threadIdx.x;
    float t = a1v + att2[b * M + m];
    t = t > 0.f ? t : ALPHA * t;
    t += mask[b * M + m];
    s[j] = t;
    mx = fmaxf(mx, t);
  }
#pragma unroll
  for (int off = 32; off; off >>= 1) mx = fmaxf(mx, __shfl_xor(mx, off, 64));
  int wid = threadIdx.x >> 6;
  if ((threadIdx.x & 63) == 0) red[wid] = mx;
  __syncthreads();
  mx = fmaxf(fmaxf(red[0], red[1]), fmaxf(red[2], red[3]));
  float sum = 0.f;
#pragma unroll
  for (int j = 0; j < 8; ++j) {
    s[j] = __expf(s[j] - mx);
    sum += s[j];
  }
#pragma unroll
  for (int off = 32; off; off >>= 1) sum += __shfl_xor(sum, off, 64);
  if ((threadIdx.x & 63) == 0) red[4 + wid] = sum;
  __syncthreads();
  sum = red[4] + red[5] + red[6] + red[7];
  float inv = 1.f / sum;
#pragma unroll
  for (int j = 0; j < 8; ++j) {
    int m = j * 256 + threadIdx.x;
    probs[(size_t)row * M + m] = s[j] * inv;
  }
}

// ---------------------------------------------------------------------------
// K4: context = probs @ Wh2 per batch, bf16 MFMA 16x16x32.
// Tile 32 rows x 128 cols, BK=64. 4 waves in 2x2 (16 rows x 64 cols each).
// A: probs fp32 -> bf16 via VALU into padded LDS (stride 72 shorts).
// B: Wb packed layout -> one contiguous 16KB global_load_lds copy.
// ---------------------------------------------------------------------------
__global__ __launch_bounds__(256) void context_kernel(
    const float* __restrict__ probs, const ushort* __restrict__ Wb,
    float* __restrict__ ctx) {
  __shared__ short ldsA[32][72];        // 32 rows x 64 k bf16, pad -> 4.5 KB
  __shared__ ushort ldsB[8 * 128 * 8];  // 8 groups x 128 n x 8 k = 16 KB
  int rt = blockIdx.x & 63;
  int b  = blockIdx.x >> 6;
  int row0 = b * N + rt * 32;
  int t = threadIdx.x;
  int lane = t & 63;
  int w = t >> 6;
  int quad = lane >> 4;
  int l16 = lane & 15;
  int m0w = (w & 1) * 16;    // wave's 16-row slice within the 32-row tile
  int n0w = (w >> 1) * 64;   // wave's 64-col slice within 128 cols
  int ar = t >> 3;           // A-staging row 0..31
  int ak = (t & 7) * 8;      // A-staging k base 0..56

  f32x4 acc[4] = {};

  for (int k0 = 0; k0 < M; k0 += 64) {
    // --- stage A: 32 x 64 fp32 -> bf16 ---
    const float* ap = probs + (size_t)(row0 + ar) * M + k0 + ak;
    float4 p0 = *(const float4*)ap;
    float4 p1 = *(const float4*)(ap + 4);
    bf16x8 av;
    av[0] = (short)f2bf(p0.x); av[1] = (short)f2bf(p0.y);
    av[2] = (short)f2bf(p0.z); av[3] = (short)f2bf(p0.w);
    av[4] = (short)f2bf(p1.x); av[5] = (short)f2bf(p1.y);
    av[6] = (short)f2bf(p1.z); av[7] = (short)f2bf(p1.w);
    *(bf16x8*)&ldsA[ar][ak] = av;
    // --- stage B: contiguous 16 KB (8 groups x 128 e x 8 k bf16) ---
    {
      const char* g =
          (const char*)(Wb + (size_t)(b * 256 + (k0 >> 3)) * 128 * 8);
      char* l = (char*)ldsB;
      int base = w * 4096 + lane * 16;
#pragma unroll
      for (int i = 0; i < 4; ++i) {
        int off = base + i * 1024;
        __builtin_amdgcn_global_load_lds(
            (const __attribute__((address_space(1))) void*)(g + off),
            (__attribute__((address_space(3))) void*)(l + off), 16, 0, 0);
      }
    }
    __syncthreads();
#pragma unroll
    for (int ks = 0; ks < 64; ks += 32) {
      bf16x8 af = *(const bf16x8*)&ldsA[m0w + l16][ks + quad * 8];
      int gl = (ks >> 3) + quad;
#pragma unroll
      for (int cf = 0; cf < 4; ++cf) {
        int n = n0w + cf * 16 + l16;
        bf16x8 bf = *(const bf16x8*)&ldsB[((size_t)gl * 128 + n) * 8];
        acc[cf] =
            __builtin_amdgcn_mfma_f32_16x16x32_bf16(af, bf, acc[cf], 0, 0, 0);
      }
    }
    __syncthreads();
  }
  // epilogue: C/D layout col=lane&15, row=quad*4+reg
#pragma unroll
  for (int cf = 0; cf < 4; ++cf) {
    int nn = n0w + cf * 16 + l16;
#pragma unroll
    for (int reg = 0; reg < 4; ++reg) {
      int rr = row0 + m0w + quad * 4 + reg;
      ctx[(size_t)rr * E + nn] = acc[cf][reg];
    }
  }
}

extern "C" void kernel_launch(void* const* d_in, const int* in_sizes, int n_in,
                              void* d_out, int out_size, void* d_ws,
                              size_t ws_size, hipStream_t stream) {
  (void)in_sizes; (void)n_in; (void)out_size; (void)ws_size;
  const float* in1  = (const float*)d_in[0];  // (B,N,DIN)
  const float* in2  = (const float*)d_in[1];  // (B,M,DIN)
  const float* mask = (const float*)d_in[2];  // (B,1,M)
  const float* W1   = (const float*)d_in[3];  // (DIN,E)
  const float* a1   = (const float*)d_in[4];  // (2E,1)

  float* ws   = (float*)d_ws;
  float* v1   = ws;                 // 256
  float* v2   = v1 + DIN;           // 256
  float* att1 = v2 + DIN;           // B*N
  float* att2 = att1 + B * N;       // B*M
  ushort* Wb  = (ushort*)(att2 + B * M);  // B*M*E bf16 packed (8.4 MB)

  float* ctx   = (float*)d_out;                 // B*N*E
  float* probs = ctx + (size_t)B * N * E;       // B*N*M

  hipLaunchKernelGGL(prep_v_kernel, dim3(1), dim3(256), 0, stream, W1, a1, v1, v2);
  hipLaunchKernelGGL(att_kernel, dim3((B * N + B * M) / 4), dim3(256), 0, stream,
                     in1, in2, v1, v2, att1, att2);
  hipLaunchKernelGGL(wh2_kernel, dim3(B * M / 32), dim3(256), 0, stream,
                     in2, W1, Wb);
  hipLaunchKernelGGL(softmax_kernel, dim3(B * N), dim3(256), 0, stream,
                     att1, att2, mask, probs);
  hipLaunchKernelGGL(context_kernel, dim3(B * N / 32), dim3(256), 0, stream,
                     probs, Wb, ctx);
}